// Round 5
// baseline (210.675 us; speedup 1.0000x reference)
//
#include <hip/hip_runtime.h>

#define BB 8
#define TT 4096
#define CC 512
#define NCHUNK 128
#define LCHUNK (TT / NCHUNK)   // 32
#define NL (CC / 2)            // 256 float4 lanes per (b,t) row

typedef float floatx4 __attribute__((ext_vector_type(4)));

// Kernel A: per-chunk local scan with zero initial state. Each thread owns
// channels 2*tid, 2*tid+1. Writes the chunk-END state (float4 = r0,i0,r1,i1)
// into the FIRST output row of this chunk's own tile (scratch-in-out; d_ws
// is never touched). x is read once from HBM and left hot in L3 for kernel C.
__global__ __launch_bounds__(256, 4) void rec_ends(
    const float* __restrict__ x,
    const float* __restrict__ Ar,
    const float* __restrict__ Ai,
    float4* __restrict__ out)
{
    const int tid   = threadIdx.x;
    const int b     = blockIdx.x / NCHUNK;
    const int chunk = blockIdx.x % NCHUNK;
    const int t0    = chunk * LCHUNK;

    const float2 a_r = ((const float2*)Ar)[tid];
    const float2 a_i = ((const float2*)Ai)[tid];
    const float2* xp = (const float2*)(x + (size_t)(b * TT + t0) * CC) + tid;

    float hr0 = 0.f, hi0 = 0.f, hr1 = 0.f, hi1 = 0.f;
#pragma unroll 8
    for (int t = 0; t < LCHUNK; ++t) {
        float2 xv = xp[(size_t)t * NL];
        float nr0 = fmaf(hr0, a_r.x, fmaf(-hi0, a_i.x, xv.x));
        float ni0 = fmaf(a_i.x, hr0, a_r.x * hi0);
        float nr1 = fmaf(hr1, a_r.y, fmaf(-hi1, a_i.y, xv.y));
        float ni1 = fmaf(a_i.y, hr1, a_r.y * hi1);
        hr0 = nr0; hi0 = ni0; hr1 = nr1; hi1 = ni1;
    }
    out[(size_t)(b * TT + t0) * NL + tid] = make_float4(hr0, hi0, hr1, hi1);
}

// Kernel B: hierarchical scan over the 128 chunk-end slots. One block per
// batch, one thread per float4 lane (256 lanes = all 512 channels). Replaces
// each END slot with the chunk-START state:
//   S_0 = h0;  slot[j]: E_j -> S_j;  S_{j+1} = A^L * S_j + E_j.
// Slot addresses are independent of the recurrence -> loads pipeline ahead;
// only the short complex-FMA chain is serial (~128 x 20 cy).
__global__ __launch_bounds__(256, 1) void rec_scan(
    const float* __restrict__ Ar,
    const float* __restrict__ Ai,
    const float* __restrict__ h0r,
    const float* __restrict__ h0i,
    float4* __restrict__ out)
{
    const int tid = threadIdx.x;     // float4 lane in [0,256)
    const int b   = blockIdx.x;      // batch

    const float2 a_r = ((const float2*)Ar)[tid];
    const float2 a_i = ((const float2*)Ai)[tid];

    // A^LCHUNK per channel (LCHUNK = 32 -> 5 complex squarings)
    float p0r = a_r.x, p0i = a_i.x, p1r = a_r.y, p1i = a_i.y;
#pragma unroll
    for (int s = 0; s < 5; ++s) {
        float n0r = p0r * p0r - p0i * p0i, n0i = 2.f * p0r * p0i;
        float n1r = p1r * p1r - p1i * p1i, n1i = 2.f * p1r * p1i;
        p0r = n0r; p0i = n0i; p1r = n1r; p1i = n1i;
    }

    const float2 h0rv = ((const float2*)(h0r + (size_t)b * CC))[tid];
    const float2 h0iv = ((const float2*)(h0i + (size_t)b * CC))[tid];
    float sr0 = h0rv.x, sr1 = h0rv.y, si0 = h0iv.x, si1 = h0iv.y;

    float4* q = out + (size_t)b * TT * NL + tid;
#pragma unroll 8
    for (int j = 0; j < NCHUNK; ++j) {
        float4 e = *q;                              // END of chunk j
        *q = make_float4(sr0, si0, sr1, si1);       // START of chunk j
        float nr0 = p0r * sr0 - p0i * si0 + e.x;
        float ni0 = p0i * sr0 + p0r * si0 + e.y;
        float nr1 = p1r * sr1 - p1i * si1 + e.z;
        float ni1 = p1i * sr1 + p1r * si1 + e.w;
        sr0 = nr0; si0 = ni0; sr1 = nr1; si1 = ni1;
        q += (size_t)LCHUNK * NL;
    }
}

// Kernel C: read own chunk-START slot (single load, replaces the old
// O(NCHUNK^2) prefix walk), register-stage the x tile (L3-hot from kernel A),
// emit all 32 steps with nontemporal stores (out is never re-read).
__global__ __launch_bounds__(256, 4) void rec_emit(
    const float* __restrict__ x,
    const float* __restrict__ Ar,
    const float* __restrict__ Ai,
    const float4* __restrict__ start,
    float4* __restrict__ out)
{
    const int tid   = threadIdx.x;
    const int b     = blockIdx.x / NCHUNK;
    const int chunk = blockIdx.x % NCHUNK;
    const int t0    = chunk * LCHUNK;

    // Issue the start-slot load first; x loads fill the latency behind it.
    const size_t slot_idx = (size_t)(b * TT + t0) * NL + tid;
    float4 s = start[slot_idx];

    const float2* xp = (const float2*)(x + (size_t)(b * TT + t0) * CC) + tid;
    float2 xs[LCHUNK];
#pragma unroll
    for (int t = 0; t < LCHUNK; ++t)
        xs[t] = xp[(size_t)t * NL];

    const float2 a_r = ((const float2*)Ar)[tid];
    const float2 a_i = ((const float2*)Ai)[tid];

    float hr0 = s.x, hi0 = s.y, hr1 = s.z, hi1 = s.w;
    floatx4* op = (floatx4*)(out + slot_idx);
#pragma unroll
    for (int t = 0; t < LCHUNK; ++t) {
        float2 xv = xs[t];
        float nr0 = fmaf(hr0, a_r.x, fmaf(-hi0, a_i.x, xv.x));
        float ni0 = fmaf(a_i.x, hr0, a_r.x * hi0);
        float nr1 = fmaf(hr1, a_r.y, fmaf(-hi1, a_i.y, xv.y));
        float ni1 = fmaf(a_i.y, hr1, a_r.y * hi1);
        hr0 = nr0; hi0 = ni0; hr1 = nr1; hi1 = ni1;
        floatx4 v = {nr0, ni0, nr1, ni1};
        __builtin_nontemporal_store(v, &op[(size_t)t * NL]);
    }
}

extern "C" void kernel_launch(void* const* d_in, const int* in_sizes, int n_in,
                              void* d_out, int out_size, void* d_ws, size_t ws_size,
                              hipStream_t stream) {
    const float* x   = (const float*)d_in[0];
    const float* Ar  = (const float*)d_in[1];
    const float* Ai  = (const float*)d_in[2];
    const float* h0r = (const float*)d_in[3];
    const float* h0i = (const float*)d_in[4];
    float4* out = (float4*)d_out;

    rec_ends<<<BB * NCHUNK, 256, 0, stream>>>(x, Ar, Ai, out);
    rec_scan<<<BB, 256, 0, stream>>>(Ar, Ai, h0r, h0i, out);
    rec_emit<<<BB * NCHUNK, 256, 0, stream>>>(x, Ar, Ai, out, out);
}

// Round 6
// 208.858 us; speedup vs baseline: 1.0087x; 1.0087x over previous
//
#include <hip/hip_runtime.h>

#define BB 8
#define TT 4096
#define CC 512
#define NCHUNK 128
#define LCHUNK (TT / NCHUNK)   // 32
#define NL (CC / 2)            // 256 float4 lanes per (b,t) row
#define PF 16                  // rec_scan prefetch depth

typedef float floatx4 __attribute__((ext_vector_type(4)));

// Kernel A: per-chunk local scan with zero initial state. Each thread owns
// channels 2*tid, 2*tid+1. Writes the chunk-END state (float4 = r0,i0,r1,i1)
// into the FIRST output row of this chunk's own tile (scratch-in-out; d_ws
// is never touched). Pure streaming read: max occupancy (32 waves/CU).
__global__ __launch_bounds__(256, 8) void rec_ends(
    const float* __restrict__ x,
    const float* __restrict__ Ar,
    const float* __restrict__ Ai,
    float4* __restrict__ out)
{
    const int tid   = threadIdx.x;
    const int b     = blockIdx.x / NCHUNK;
    const int chunk = blockIdx.x % NCHUNK;
    const int t0    = chunk * LCHUNK;

    const float2 a_r = ((const float2*)Ar)[tid];
    const float2 a_i = ((const float2*)Ai)[tid];
    const float2* xp = (const float2*)(x + (size_t)(b * TT + t0) * CC) + tid;

    float hr0 = 0.f, hi0 = 0.f, hr1 = 0.f, hi1 = 0.f;
#pragma unroll 8
    for (int t = 0; t < LCHUNK; ++t) {
        float2 xv = xp[(size_t)t * NL];
        float nr0 = fmaf(hr0, a_r.x, fmaf(-hi0, a_i.x, xv.x));
        float ni0 = fmaf(a_i.x, hr0, a_r.x * hi0);
        float nr1 = fmaf(hr1, a_r.y, fmaf(-hi1, a_i.y, xv.y));
        float ni1 = fmaf(a_i.y, hr1, a_r.y * hi1);
        hr0 = nr0; hi0 = ni0; hr1 = nr1; hi1 = ni1;
    }
    out[(size_t)(b * TT + t0) * NL + tid] = make_float4(hr0, hi0, hr1, hi1);
}

// Kernel B: hierarchical scan over the 128 chunk-end slots. One block per
// batch, one thread per float4 lane. Rolling PF-deep register prefetch keeps
// 16 slot loads in flight, so the only serial cost is the 128-step complex
// FMA chain (~1 us). Each slot: E_j -> S_j (chunk-START);
// S_0 = h0, S_{j+1} = A^L * S_j + E_j.
__global__ __launch_bounds__(256, 1) void rec_scan(
    const float* __restrict__ Ar,
    const float* __restrict__ Ai,
    const float* __restrict__ h0r,
    const float* __restrict__ h0i,
    float4* __restrict__ out)
{
    const int tid = threadIdx.x;     // float4 lane in [0,256)
    const int b   = blockIdx.x;      // batch

    const float2 a_r = ((const float2*)Ar)[tid];
    const float2 a_i = ((const float2*)Ai)[tid];

    // A^LCHUNK per channel (LCHUNK = 32 -> 5 complex squarings)
    float p0r = a_r.x, p0i = a_i.x, p1r = a_r.y, p1i = a_i.y;
#pragma unroll
    for (int s = 0; s < 5; ++s) {
        float n0r = p0r * p0r - p0i * p0i, n0i = 2.f * p0r * p0i;
        float n1r = p1r * p1r - p1i * p1i, n1i = 2.f * p1r * p1i;
        p0r = n0r; p0i = n0i; p1r = n1r; p1i = n1i;
    }

    const float2 h0rv = ((const float2*)(h0r + (size_t)b * CC))[tid];
    const float2 h0iv = ((const float2*)(h0i + (size_t)b * CC))[tid];
    float sr0 = h0rv.x, sr1 = h0rv.y, si0 = h0iv.x, si1 = h0iv.y;

    float4* q = out + (size_t)b * TT * NL + tid;
    const size_t cstride = (size_t)LCHUNK * NL;   // float4s between chunk slots

    // Preload first PF slots (statically indexed -> registers).
    float4 e[PF];
#pragma unroll
    for (int k = 0; k < PF; ++k)
        e[k] = q[(size_t)k * cstride];

    for (int j0 = 0; j0 < NCHUNK; j0 += PF) {
#pragma unroll
        for (int k = 0; k < PF; ++k) {
            const int j = j0 + k;
            float4 ev = e[k];
            q[(size_t)j * cstride] = make_float4(sr0, si0, sr1, si1); // S_j
            if (j + PF < NCHUNK)                     // prefetch slot j+PF
                e[k] = q[(size_t)(j + PF) * cstride];
            float nr0 = p0r * sr0 - p0i * si0 + ev.x;
            float ni0 = p0i * sr0 + p0r * si0 + ev.y;
            float nr1 = p1r * sr1 - p1i * si1 + ev.z;
            float ni1 = p1i * sr1 + p1r * si1 + ev.w;
            sr0 = nr0; si0 = ni0; sr1 = nr1; si1 = ni1;
        }
    }
}

// Kernel C: read own chunk-START slot (single load), register-stage the x
// tile (L2/L3-hot from kernel A), emit all 32 steps with nontemporal stores.
__global__ __launch_bounds__(256, 4) void rec_emit(
    const float* __restrict__ x,
    const float* __restrict__ Ar,
    const float* __restrict__ Ai,
    const float4* __restrict__ start,
    float4* __restrict__ out)
{
    const int tid   = threadIdx.x;
    const int b     = blockIdx.x / NCHUNK;
    const int chunk = blockIdx.x % NCHUNK;
    const int t0    = chunk * LCHUNK;

    // Issue the start-slot load first; x loads fill the latency behind it.
    const size_t slot_idx = (size_t)(b * TT + t0) * NL + tid;
    float4 s = start[slot_idx];

    const float2* xp = (const float2*)(x + (size_t)(b * TT + t0) * CC) + tid;
    float2 xs[LCHUNK];
#pragma unroll
    for (int t = 0; t < LCHUNK; ++t)
        xs[t] = xp[(size_t)t * NL];

    const float2 a_r = ((const float2*)Ar)[tid];
    const float2 a_i = ((const float2*)Ai)[tid];

    float hr0 = s.x, hi0 = s.y, hr1 = s.z, hi1 = s.w;
    floatx4* op = (floatx4*)(out + slot_idx);
#pragma unroll
    for (int t = 0; t < LCHUNK; ++t) {
        float2 xv = xs[t];
        float nr0 = fmaf(hr0, a_r.x, fmaf(-hi0, a_i.x, xv.x));
        float ni0 = fmaf(a_i.x, hr0, a_r.x * hi0);
        float nr1 = fmaf(hr1, a_r.y, fmaf(-hi1, a_i.y, xv.y));
        float ni1 = fmaf(a_i.y, hr1, a_r.y * hi1);
        hr0 = nr0; hi0 = ni0; hr1 = nr1; hi1 = ni1;
        floatx4 v = {nr0, ni0, nr1, ni1};
        __builtin_nontemporal_store(v, &op[(size_t)t * NL]);
    }
}

extern "C" void kernel_launch(void* const* d_in, const int* in_sizes, int n_in,
                              void* d_out, int out_size, void* d_ws, size_t ws_size,
                              hipStream_t stream) {
    const float* x   = (const float*)d_in[0];
    const float* Ar  = (const float*)d_in[1];
    const float* Ai  = (const float*)d_in[2];
    const float* h0r = (const float*)d_in[3];
    const float* h0i = (const float*)d_in[4];
    float4* out = (float4*)d_out;

    rec_ends<<<BB * NCHUNK, 256, 0, stream>>>(x, Ar, Ai, out);
    rec_scan<<<BB, 256, 0, stream>>>(Ar, Ai, h0r, h0i, out);
    rec_emit<<<BB * NCHUNK, 256, 0, stream>>>(x, Ar, Ai, out, out);
}